// Round 1
// baseline (507.933 us; speedup 1.0000x reference)
//
#include <hip/hip_runtime.h>
#include <math.h>

#define HASH_SIZE_LOG2 19
#define HASH_MASK ((1u << HASH_SIZE_LOG2) - 1u)
#define HS (1u << HASH_SIZE_LOG2)
#define NUM_LEVELS 16

struct ResArr { float r[NUM_LEVELS]; };

// thread layout: 256 threads/block = 32 points x 8 level-pairs.
// tid = local_point*8 + lp ; thread handles levels (2lp, 2lp+1) of its point.
// Output write: thread writes float4 at out[n*32 + lp*4] -> a wave covers
// 64*16B = 1KB contiguous output, fully coalesced.
__global__ __launch_bounds__(256) void HashEncoder_67963562492047_kernel(
    const float* __restrict__ x,      // [N,3] f32
    const float* __restrict__ emb,    // [16][HS][2] f32
    float* __restrict__ out,          // [N,32] f32
    ResArr res, int n_points)
{
    __shared__ float sx[32 * 3];   // 32 points' coords
    __shared__ float sres[NUM_LEVELS];

    const int t = threadIdx.x;
    const long long base_pt = (long long)blockIdx.x * 32;

    // cooperative coalesced load of 96 floats of x
    if (t < 96) {
        long long gi = base_pt * 3 + t;
        sx[t] = (gi < (long long)n_points * 3) ? x[gi] : 0.0f;
    }
    // resolutions: uniform constant indices (kernarg scalar loads), one writer
    if (t == 0) {
        #pragma unroll
        for (int i = 0; i < NUM_LEVELS; i++) sres[i] = res.r[i];
    }
    __syncthreads();

    const int lp = t & 7;          // level-pair 0..7
    const int pl = t >> 3;         // local point 0..31
    const long long n = base_pt + pl;
    if (n >= n_points) return;

    const float x0 = sx[pl * 3 + 0];
    const float x1 = sx[pl * 3 + 1];
    const float x2 = sx[pl * 3 + 2];

    const unsigned P1 = 2654435761u, P2 = 805459861u;
    const int l0 = lp * 2;

    float4 v;
    #pragma unroll
    for (int k = 0; k < 2; k++) {
        const int l = l0 + k;
        const float r = sres[l];
        // exact f32 multiply + floor, matching jnp.floor(x * res) in float32.
        // x in [0,1), r <= 2048 -> product < 2048, non-negative.
        unsigned c0 = (unsigned)(int)floorf(x0 * r);
        unsigned c1 = (unsigned)(int)floorf(x1 * r);
        unsigned c2 = (unsigned)(int)floorf(x2 * r);
        // int64 (c0 + c1*P1 + c2*P2) % 2^19 == uint32-wrapped sum & mask,
        // since 2^19 | 2^32 and all terms are non-negative.
        unsigned h = (c0 + c1 * P1 + c2 * P2) & HASH_MASK;
        const float2 f = ((const float2*)emb)[(size_t)l * HS + h];
        if (k == 0) { v.x = f.x; v.y = f.y; }
        else        { v.z = f.x; v.w = f.y; }
    }
    ((float4*)out)[n * 8 + lp] = v;
}

extern "C" void kernel_launch(void* const* d_in, const int* in_sizes, int n_in,
                              void* d_out, int out_size, void* d_ws, size_t ws_size,
                              hipStream_t stream) {
    const float* x   = (const float*)d_in[0];
    const float* emb = (const float*)d_in[1];
    float* out = (float*)d_out;
    const int n = in_sizes[0] / 3;

    // Replicate RESOLUTIONS exactly as the reference's host Python computes it:
    // _b = (2048/16) ** (1.0/15);  res[i] = int(16 * _b**i)  (truncation).
    // CPython float.__pow__ calls the platform libm pow(), same as here, so
    // the borderline level 15 (exact value 2048.0) truncates identically.
    ResArr res;
    const double b = pow(128.0, 1.0 / 15.0);
    for (int i = 0; i < NUM_LEVELS; i++) {
        res.r[i] = (float)(long long)(16.0 * pow(b, (double)i));
    }

    const int blocks = (n + 31) / 32;   // 32 points per block
    HashEncoder_67963562492047_kernel<<<blocks, 256, 0, stream>>>(x, emb, out, res, n);
}